// Round 8
// baseline (192.691 us; speedup 1.0000x reference)
//
#include <hip/hip_runtime.h>

// Y = X @ Q where Q is a 512x512 permutation (one-hot) matrix.
// Equivalent to a column gather: Y[n][j] = X[n][map[j]], map[j] = argmax_d Q[d][j].
//
// Memory-bound: 1.074 GB HBM traffic, roofline ~171 us @ 6.29 TB/s measured ceiling.
// This version: R7's barrier-free wave-autonomous structure + 2-deep counted-vmcnt
// pipeline (T4): each wave handles 4 rows in 1-row chunks, double-buffered, waiting
// vmcnt(N) for only the current chunk (N = younger in-flight ops; vmcnt decrements
// in issue order). Next row's HBM loads stay in flight under the current gather.
// sched_barrier(0) pins region order so the counted waits match emitted code.

#define DCOLS 512
#define ROWS_PER_WAVE 4
#define THREADS 256
#define WAVES_PER_BLOCK (THREADS / 64)

typedef float f32x4 __attribute__((ext_vector_type(4)));
typedef int   i32x4 __attribute__((ext_vector_type(4)));

typedef __attribute__((address_space(1))) const void g_void;
typedef __attribute__((address_space(3))) void lds_void;

#define SB()     __builtin_amdgcn_sched_barrier(0)
#define WAITVM(N) asm volatile("s_waitcnt vmcnt(" #N ")" ::: "memory")
#define LGKM0()  asm volatile("s_waitcnt lgkmcnt(0)" ::: "memory")

__global__ __launch_bounds__(256)
void build_map_kernel(const float* __restrict__ Q, int* __restrict__ map) {
    int idx = blockIdx.x * 256 + threadIdx.x;   // idx = d*512 + j
    if (idx < DCOLS * DCOLS) {
        if (Q[idx] > 0.5f) {
            map[idx & (DCOLS - 1)] = idx >> 9;  // map[j] = d
        }
    }
}

__global__ __launch_bounds__(THREADS)
void permute_gather_kernel(const float* __restrict__ X,
                           const int* __restrict__ map,
                           float* __restrict__ out) {
    // Per-wave double slab: 2 x 1 row = 4 KiB. Block 16 KiB -> 8 blocks/CU, 32 waves.
    __shared__ float lds[WAVES_PER_BLOCK][2][DCOLS];

    const int t  = threadIdx.x;
    const int wv = t >> 6;
    const int l  = t & 63;

    const i32x4 m0 = ((const i32x4*)map)[l];
    const i32x4 m1 = ((const i32x4*)map)[l + 64];

    const long long r0 =
        ((long long)blockIdx.x * WAVES_PER_BLOCK + wv) * ROWS_PER_WAVE;

    float* slab[2] = { lds[wv][0], lds[wv][1] };

    // Issue one row's loads: 2 x (64 lanes x 16B) = 2 KiB, per-lane src + lds addr.
    auto stage = [&](float* s, int r) {
        const float* src = X + (r0 + r) * DCOLS + l * 4;
        __builtin_amdgcn_global_load_lds((g_void*)(src),
                                         (lds_void*)(s + l * 4), 16, 0, 0);
        __builtin_amdgcn_global_load_lds((g_void*)(src + 256),
                                         (lds_void*)(s + 256 + l * 4), 16, 0, 0);
    };
    auto gather = [&](const float* row, f32x4& o0, f32x4& o1) {
        o0.x = row[m0.x]; o0.y = row[m0.y]; o0.z = row[m0.z]; o0.w = row[m0.w];
        o1.x = row[m1.x]; o1.y = row[m1.y]; o1.z = row[m1.z]; o1.w = row[m1.w];
    };
    auto store = [&](int r, f32x4 o0, f32x4 o1) {
        f32x4* dst = (f32x4*)(out + (r0 + r) * DCOLS);
        __builtin_nontemporal_store(o0, &dst[l]);
        __builtin_nontemporal_store(o1, &dst[l + 64]);
    };

    f32x4 o0, o1;

    // Prologue: chunks C0, C1 in flight (4 VMEM ops).
    stage(slab[0], 0);
    stage(slab[1], 1);
    SB();

    // r=0: wait C0 (younger: C1 = 2). gather, then C2 overwrites slab0 only
    // after the ds_reads completed (lgkmcnt 0). Then stores (issue after loads).
    WAITVM(2); SB();
    gather(slab[0], o0, o1);
    LGKM0(); SB();
    stage(slab[0], 2);
    store(0, o0, o1); SB();

    // r=1: wait C1 (younger: C2 + st0 = 4).
    WAITVM(4); SB();
    gather(slab[1], o0, o1);
    LGKM0(); SB();
    stage(slab[1], 3);
    store(1, o0, o1); SB();

    // r=2: wait C2 (younger: st0 + C3 + st1 = 6).
    WAITVM(6); SB();
    gather(slab[0], o0, o1);
    LGKM0(); SB();
    store(2, o0, o1); SB();

    // r=3: wait C3 (younger: st1 + st2 = 4).
    WAITVM(4); SB();
    gather(slab[1], o0, o1);
    store(3, o0, o1);
}

extern "C" void kernel_launch(void* const* d_in, const int* in_sizes, int n_in,
                              void* d_out, int out_size, void* d_ws, size_t ws_size,
                              hipStream_t stream) {
    const float* X = (const float*)d_in[0];
    const float* Q = (const float*)d_in[1];
    float* out = (float*)d_out;
    int* map = (int*)d_ws;   // 512 ints = 2 KiB scratch

    const int N = in_sizes[0] / DCOLS;                               // 262144
    const int rows_per_block = WAVES_PER_BLOCK * ROWS_PER_WAVE;      // 16
    const int nblocks = N / rows_per_block;                          // 16384

    build_map_kernel<<<(DCOLS * DCOLS + 255) / 256, 256, 0, stream>>>(Q, map);
    permute_gather_kernel<<<nblocks, THREADS, 0, stream>>>(X, map, out);
}